// Round 3
// baseline (2456.572 us; speedup 1.0000x reference)
//
#include <hip/hip_runtime.h>
#include <hip/hip_bf16.h>
#include <hip/hip_fp16.h>

#define D   64
#define HID 36
#define NZ  72      // 2*HID z-rows (sent | recv)
#define NZP 80      // padded to 5 mfma 16-row tiles

typedef __attribute__((ext_vector_type(8))) short short8;   // 8 x bf16
typedef __attribute__((ext_vector_type(4))) float f32x4;

__device__ inline short f2bf(float f) {
    __hip_bfloat16 h = __float2bfloat16(f);
    return *reinterpret_cast<short*>(&h);
}
__device__ inline unsigned pack_h2(float a, float b) {
    __half2 h = __floats2half2_rn(a, b);
    return *reinterpret_cast<unsigned*>(&h);
}
__device__ inline void pk_atomic_add_f16(__half* addr, unsigned data) {
    asm volatile("global_atomic_pk_add_f16 %0, %1, off"
                 :: "v"(addr), "v"(data) : "memory");
}

// ---------------------------------------------------------------------------
__global__ void zero_ws_kernel(float4* __restrict__ p, long n4) {
    long i = (long)blockIdx.x * blockDim.x + threadIdx.x;
    long stride = (long)gridDim.x * blockDim.x;
    float4 z = make_float4(0.f, 0.f, 0.f, 0.f);
    for (; i < n4; i += stride) p[i] = z;
}

// ---------------------------------------------------------------------------
// Fused projection + scatter.
// Per wave: 16 edges. z[e] = edges[e] @ W1[64:192]  (72 outputs: 36 sent, 36 recv)
// via 5 x (2 x mfma_f32_16x16x32_bf16): A = W^T tile [16 zrows x 64k] (LDS),
// B = edges^T [64k x 16 edges] (registers). D: col(lane&15)=edge,
// row(4*(lane>>4)+reg)=zrow -> each lane holds 4 consecutive z-rows of one
// edge -> 2 packed-f16 atomics per tile.
// ---------------------------------------------------------------------------
__global__ __launch_bounds__(256) void pscatter_kernel(
    const float* __restrict__ edges,
    const int* __restrict__ senders,
    const int* __restrict__ receivers,
    const float* __restrict__ W1,      // [192][36] f32 row-major
    __half* __restrict__ sent_z,       // [n_nodes][36] fp16, pre-zeroed
    __half* __restrict__ recv_z,       // [n_nodes][36] fp16, pre-zeroed
    long n_edges)
{
    __shared__ short WT[NZP * 64];     // bf16 bits: WT[zr][k], zr>=72 zero

    int tid = threadIdx.x;
    for (int idx = tid; idx < NZP * 64; idx += 256) {
        int zr = idx >> 6, k = idx & 63;
        float v = 0.f;
        if (zr < HID)      v = W1[(64 + k) * HID + zr];          // sent block
        else if (zr < NZ)  v = W1[(128 + k) * HID + (zr - HID)]; // recv block
        WT[idx] = f2bf(v);
    }
    __syncthreads();

    long wave_id = (long)blockIdx.x * 4 + (tid >> 6);
    int lane = tid & 63;
    long e_base = wave_id * 16;
    if (e_base >= n_edges) return;

    int er = lane & 15;        // edge-within-tile (B col / A row / D col)
    int kg = lane >> 4;        // k-group 0..3
    long e = e_base + er;
    bool ev = (e < n_edges);
    long ecl = ev ? e : (n_edges - 1);

    // B fragments: edges[e][k], k = h*32 + kg*8 + j
    const float* erow = edges + ecl * D;
    short8 bfrag[2];
#pragma unroll
    for (int h = 0; h < 2; ++h) {
        float4 x0 = *reinterpret_cast<const float4*>(erow + h * 32 + kg * 8);
        float4 x1 = *reinterpret_cast<const float4*>(erow + h * 32 + kg * 8 + 4);
        short8 b;
        b[0] = f2bf(x0.x); b[1] = f2bf(x0.y); b[2] = f2bf(x0.z); b[3] = f2bf(x0.w);
        b[4] = f2bf(x1.x); b[5] = f2bf(x1.y); b[6] = f2bf(x1.z); b[7] = f2bf(x1.w);
        bfrag[h] = b;
    }

    // A fragments from LDS: WT[(t*16+er)][h*32 + kg*8 + j]
    f32x4 acc[5];
#pragma unroll
    for (int t = 0; t < 5; ++t) {
        acc[t][0] = 0.f; acc[t][1] = 0.f; acc[t][2] = 0.f; acc[t][3] = 0.f;
        short8 a0 = *reinterpret_cast<const short8*>(&WT[(t * 16 + er) * 64 + kg * 8]);
        short8 a1 = *reinterpret_cast<const short8*>(&WT[(t * 16 + er) * 64 + 32 + kg * 8]);
        acc[t] = __builtin_amdgcn_mfma_f32_16x16x32_bf16(a0, bfrag[0], acc[t], 0, 0, 0);
        acc[t] = __builtin_amdgcn_mfma_f32_16x16x32_bf16(a1, bfrag[1], acc[t], 0, 0, 0);
    }

    int s = ev ? senders[e] : 0;
    int r = ev ? receivers[e] : 0;

#pragma unroll
    for (int t = 0; t < 5; ++t) {
        int zr0 = t * 16 + kg * 4;         // first of 4 consecutive z-rows
        if (zr0 >= NZ) continue;           // padding rows (t=4, kg>=2)
        bool is_sent = (zr0 < HID);
        int node = is_sent ? s : r;
        __half* base = is_sent ? (sent_z + (long)node * HID + zr0)
                               : (recv_z + (long)node * HID + (zr0 - HID));
        unsigned u01 = pack_h2(acc[t][0], acc[t][1]);
        unsigned u23 = pack_h2(acc[t][2], acc[t][3]);
        if (ev) {
            pk_atomic_add_f16(base,     u01);
            pk_atomic_add_f16(base + 2, u23);
        }
    }
}

// ---------------------------------------------------------------------------
// Per-node MLP: h = relu(nodes@W1a + b1 + sent_z + recv_z); out = h@W2 + b2
// ---------------------------------------------------------------------------
__global__ __launch_bounds__(256) void mlp_kernel(
    const float* __restrict__ nodes,
    const __half* __restrict__ sent_z,
    const __half* __restrict__ recv_z,
    const float* __restrict__ W1,      // rows 0..63 used
    const float* __restrict__ b1,
    const float* __restrict__ W2,
    const float* __restrict__ b2,
    float* __restrict__ out,
    int n)
{
    __shared__ float sW1[D * HID];     // 9.2 KB
    __shared__ float sb1[HID];
    __shared__ float sW2[HID * 2];
    __shared__ float sb2[2];

    for (int t = threadIdx.x; t < D * HID; t += blockDim.x) sW1[t] = W1[t];
    if (threadIdx.x < HID)     sb1[threadIdx.x] = b1[threadIdx.x];
    if (threadIdx.x < HID * 2) sW2[threadIdx.x] = W2[threadIdx.x];
    if (threadIdx.x < 2)       sb2[threadIdx.x] = b2[threadIdx.x];
    __syncthreads();

    int node = blockIdx.x * blockDim.x + threadIdx.x;
    if (node >= n) return;

    float acc[HID];
#pragma unroll
    for (int j = 0; j < HID; ++j) acc[j] = sb1[j];

    const float* f = nodes + (long)node * D;
    for (int k = 0; k < D; k += 4) {
        float4 fv = *reinterpret_cast<const float4*>(f + k);
#pragma unroll
        for (int j = 0; j < HID; ++j) {
            acc[j] += fv.x * sW1[(k + 0) * HID + j];
            acc[j] += fv.y * sW1[(k + 1) * HID + j];
            acc[j] += fv.z * sW1[(k + 2) * HID + j];
            acc[j] += fv.w * sW1[(k + 3) * HID + j];
        }
    }

    const __half2* sz = reinterpret_cast<const __half2*>(sent_z + (long)node * HID);
    const __half2* rz = reinterpret_cast<const __half2*>(recv_z + (long)node * HID);
#pragma unroll
    for (int j = 0; j < HID / 2; ++j) {
        float2 a = __half22float2(sz[j]);
        float2 b = __half22float2(rz[j]);
        acc[2 * j]     += a.x + b.x;
        acc[2 * j + 1] += a.y + b.y;
    }

    float o0 = sb2[0], o1 = sb2[1];
#pragma unroll
    for (int j = 0; j < HID; ++j) {
        float h = fmaxf(acc[j], 0.f);
        o0 += h * sW2[j * 2 + 0];
        o1 += h * sW2[j * 2 + 1];
    }
    reinterpret_cast<float2*>(out)[node] = make_float2(o0, o1);
}

// ---------------------------------------------------------------------------
extern "C" void kernel_launch(void* const* d_in, const int* in_sizes, int n_in,
                              void* d_out, int out_size, void* d_ws, size_t ws_size,
                              hipStream_t stream) {
    const float* nodes     = (const float*)d_in[0];
    const float* edges     = (const float*)d_in[1];
    const int*   senders   = (const int*)d_in[2];
    const int*   receivers = (const int*)d_in[3];
    const float* W1        = (const float*)d_in[4];
    const float* b1        = (const float*)d_in[5];
    const float* W2        = (const float*)d_in[6];
    const float* b2        = (const float*)d_in[7];
    float* out = (float*)d_out;

    const int  n_nodes = in_sizes[0] / D;     // 100,000
    const long n_edges = in_sizes[2];         // 3,200,000

    __half* sent_z = (__half*)d_ws;                          // [n_nodes][36]
    __half* recv_z = sent_z + (long)n_nodes * HID;           // [n_nodes][36]

    // 1) zero z accumulators (14.4 MB)
    {
        long bytes = (long)2 * n_nodes * HID * sizeof(__half);
        long n4 = bytes / 16;
        zero_ws_kernel<<<2048, 256, 0, stream>>>((float4*)d_ws, n4);
    }
    // 2) fused project + scatter
    {
        long n_waves = (n_edges + 15) / 16;                  // 200,000
        int blocks = (int)((n_waves + 3) / 4);               // 50,000
        pscatter_kernel<<<blocks, 256, 0, stream>>>(edges, senders, receivers,
                                                    W1, sent_z, recv_z, n_edges);
    }
    // 3) MLP
    {
        int blocks = (n_nodes + 255) / 256;
        mlp_kernel<<<blocks, 256, 0, stream>>>(nodes, sent_z, recv_z,
                                               W1, b1, W2, b2, out, n_nodes);
    }
}